// Round 7
// baseline (2090.928 us; speedup 1.0000x reference)
//
#include <hip/hip_runtime.h>
#include <hip/hip_cooperative_groups.h>

namespace cg = cooperative_groups;

#define F 128
#define SPAD 136      // LDS stride (ushorts) for S tile
#define NR 32         // rows per tile

typedef __attribute__((ext_vector_type(8))) short short8;
typedef __attribute__((ext_vector_type(16))) float f32x16;

__device__ __forceinline__ float elu_f(float x) {
    return x > 0.f ? x : __expf(x) - 1.f;
}
__device__ __forceinline__ ushort f2bf(float x) {   // fp32 -> bf16 RNE
    unsigned u = __float_as_uint(x);
    u = (u + 0x7FFFu + ((u >> 16) & 1u)) >> 16;
    return (ushort)u;
}
__device__ __forceinline__ float bf2f(ushort u) {
    return __uint_as_float((unsigned)u << 16);
}
__device__ __forceinline__ void bfma8(float* a, float v, short8 u) {
#pragma unroll
    for (int i = 0; i < 8; ++i) a[i] += v * bf2f((ushort)u[i]);
}

struct MArgs {
    const float* inputs; const float* mask;
    const int* rows[5]; const int* cols[5]; const float* vals[5];
    const float* gW1; const float* gb1; const float* gdW; const float* gdb;
    const float* glW; const float* glb; const float* guW; const float* gub;
    const float* gW2; const float* gb2;
    const float* lW1; const float* lb1; const float* lrW; const float* lrb;
    const float* lW2; const float* lb2;
    float* out;
    float* BUF0; float* GU; float* G2; float* D8; float* D4; float* D2; float* LB;
    ushort* EB0; ushort* EG1; ushort* EG2; ushort* ED8; ushort* ED4; ushort* ED2;
    ushort* LE1; ushort* LE2;
    int* rp[5];
    float* ACC; float* DEN;
    ushort* P;   // 88 packed 128x128 bf16 halves
};

// slot config: buffer ids resolved against tables built from MArgs
struct SlotCfg {
    signed char ea, res, out, eaout;   // ea: mirror id; res/out: fp32 id; -1 none
    signed char lv;                    // lap level 0..4, -1 dense/avg
    signed char eo, ee, skip;          // epilogue buffers (fp32 id, mirror id, fp32 id)
    signed char epi;                   // 0 none, 1 maxpool2, 2 repeat2+skip
    signed char bb;                    // bias base: 0 gdb 1 glb 2 gub 3 lrb
    short wp;                          // packed half index (x16384)
    short boff;                        // bias offset (floats)
    short accin, accout;               // ACC slot (x128) or -1
    short wb;                          // lrW sublayer idx for rank-1 Wb, -1 none
    short nt;                          // tiles (n/NR)
};

__device__ const SlotCfg GS[14] = {
    {0,-1,-1, 1, 3,-1,-1,-1,0,0,  0,  0,-1,-1,-1,512},
    {1, 0,-1,-1, 3, 3, 3,-1,1,0,  2,128,-1,-1,-1,512},
    {3,-1,-1, 1, 2,-1,-1,-1,0,0,  4,256,-1,-1,-1,256},
    {1, 3,-1,-1, 2, 4, 4,-1,1,0,  6,384,-1,-1,-1,256},
    {4,-1,-1, 1, 1,-1,-1,-1,0,0,  8,512,-1,-1,-1,128},
    {1, 4,-1,-1, 1, 5, 5,-1,1,0, 10,640,-1,-1,-1,128},
    {5,-1,-1, 1, 0,-1,-1,-1,0,1, 12,  0,-1,-1,-1, 64},
    {1, 5,-1,-1, 0, 1, 2, 4,2,1, 14,128,-1,-1,-1, 64},
    {2,-1,-1, 1, 1,-1,-1,-1,0,2, 16,  0,-1,-1,-1,128},
    {1, 1,-1,-1, 1, 2, 2, 3,2,2, 18,128,-1,-1,-1,128},
    {2,-1,-1, 1, 2,-1,-1,-1,0,2, 20,256,-1,-1,-1,256},
    {1, 2,-1,-1, 2, 1, 2, 0,2,2, 22,384,-1,-1,-1,256},
    {2,-1,-1, 1, 3,-1,-1,-1,0,2, 24,512,-1,-1,-1,512},
    {1, 1,-1, 0, 3,-1,-1,-1,0,2, 26,640,-1,-1,-1,512},
};

__device__ const SlotCfg LS[30] = {
    {6,-1,-1,7, 4,-1,-1,-1,0,3, 28,   0,-1,-1,-1,512},
    {7, 6, 6,6, 4,-1,-1,-1,0,3, 30, 128,-1, 0,-1,512},
    {6,-1,-1,7,-1,-1,-1,-1,0,3, 32, 256, 0, 1, 2,512},
    {7, 6, 6,6,-1,-1,-1,-1,0,3, 34, 384, 1,-1, 3,512},
    {6,-1,-1,7, 4,-1,-1,-1,0,3, 36, 512,-1,-1,-1,512},
    {7, 6, 6,6, 4,-1,-1,-1,0,3, 38, 640,-1, 2,-1,512},
    {6,-1,-1,7,-1,-1,-1,-1,0,3, 40, 768, 2, 3, 6,512},
    {7, 6, 6,6,-1,-1,-1,-1,0,3, 42, 896, 3,-1, 7,512},
    {6,-1,-1,7, 4,-1,-1,-1,0,3, 44,1024,-1,-1,-1,512},
    {7, 6, 6,6, 4,-1,-1,-1,0,3, 46,1152,-1, 4,-1,512},
    {6,-1,-1,7,-1,-1,-1,-1,0,3, 48,1280, 4, 5,10,512},
    {7, 6, 6,6,-1,-1,-1,-1,0,3, 50,1408, 5,-1,11,512},
    {6,-1,-1,7, 4,-1,-1,-1,0,3, 52,1536,-1,-1,-1,512},
    {7, 6, 6,6, 4,-1,-1,-1,0,3, 54,1664,-1, 6,-1,512},
    {6,-1,-1,7,-1,-1,-1,-1,0,3, 56,1792, 6, 7,14,512},
    {7, 6, 6,6,-1,-1,-1,-1,0,3, 58,1920, 7,-1,15,512},
    {6,-1,-1,7, 4,-1,-1,-1,0,3, 60,2048,-1,-1,-1,512},
    {7, 6, 6,6, 4,-1,-1,-1,0,3, 62,2176,-1, 8,-1,512},
    {6,-1,-1,7,-1,-1,-1,-1,0,3, 64,2304, 8, 9,18,512},
    {7, 6, 6,6,-1,-1,-1,-1,0,3, 66,2432, 9,-1,19,512},
    {6,-1,-1,7, 4,-1,-1,-1,0,3, 68,2560,-1,-1,-1,512},
    {7, 6, 6,6, 4,-1,-1,-1,0,3, 70,2688,-1,10,-1,512},
    {6,-1,-1,7,-1,-1,-1,-1,0,3, 72,2816,10,11,22,512},
    {7, 6, 6,6,-1,-1,-1,-1,0,3, 74,2944,11,-1,23,512},
    {6,-1,-1,7, 4,-1,-1,-1,0,3, 76,3072,-1,-1,-1,512},
    {7, 6, 6,6, 4,-1,-1,-1,0,3, 78,3200,-1,12,-1,512},
    {6,-1,-1,7,-1,-1,-1,-1,0,3, 80,3328,12,13,26,512},
    {7, 6, 6,6,-1,-1,-1,-1,0,3, 82,3456,13,-1,27,512},
    {6,-1,-1,7, 4,-1,-1,-1,0,3, 84,3584,-1,-1,-1,512},
    {7, 6,-1,6, 4,-1,-1,-1,0,3, 86,3712,-1,-1,-1,512},
};

__device__ void run_layer_tile(const MArgs& A, const SlotCfg& c, int blk, ushort* SS,
                               float* const* FB, ushort* const* EB,
                               const float* const* BB) {
    const int t = threadIdx.x;
    const int rbase = blk * NR;
    const int w = t >> 6, l = t & 63, m = l & 31, kh = l >> 5;
    const int col = w * 32 + m;
    const bool lap = (c.lv >= 0);

    const ushort* EA = EB[c.ea];
    const float* RES = (c.res >= 0) ? FB[c.res] : nullptr;
    float* OUT = (c.out >= 0) ? FB[c.out] : nullptr;
    ushort* EAOUT = (c.eaout >= 0) ? EB[c.eaout] : nullptr;
    const ushort* Wp = A.P + (size_t)c.wp * 16384;
    const float* bias = BB[c.bb] + c.boff;

    // dense-half A-fragments straight from EA global (frag-exact layout)
    short8 afrag[8];
    {
        const ushort* ear = EA + (size_t)(rbase + m) * F + kh * 8;
#pragma unroll
        for (int ki = 0; ki < 8; ++ki) afrag[ki] = *(const short8*)(ear + ki * 16);
    }

    if (lap) {
        const int* rowptr = A.rp[c.lv];
        const int* cols = A.cols[c.lv];
        const float* vals = A.vals[c.lv];
        __syncthreads();   // WAR guard vs previous tile's SS reads
        const int grp = t >> 3, l8 = t & 7;
        const short8* EA8 = (const short8*)EA;
        const int chunk = l8 * 2;
        int row = rbase + grp;
        int e0 = rowptr[row], e1 = rowptr[row + 1];
        float acc0[16], acc1[16];
#pragma unroll
        for (int i = 0; i < 16; ++i) { acc0[i] = 0.f; acc1[i] = 0.f; }
        int e = e0;
        for (; e + 4 <= e1; e += 4) {
            int c0 = cols[e + 0], c1 = cols[e + 1], c2 = cols[e + 2], c3 = cols[e + 3];
            float v0 = vals[e + 0], v1 = vals[e + 1], v2 = vals[e + 2], v3 = vals[e + 3];
            short8 u0a = EA8[(size_t)c0 * 16 + chunk], u0b = EA8[(size_t)c0 * 16 + chunk + 1];
            short8 u1a = EA8[(size_t)c1 * 16 + chunk], u1b = EA8[(size_t)c1 * 16 + chunk + 1];
            short8 u2a = EA8[(size_t)c2 * 16 + chunk], u2b = EA8[(size_t)c2 * 16 + chunk + 1];
            short8 u3a = EA8[(size_t)c3 * 16 + chunk], u3b = EA8[(size_t)c3 * 16 + chunk + 1];
            bfma8(acc0, v0, u0a); bfma8(acc0 + 8, v0, u0b);
            bfma8(acc1, v1, u1a); bfma8(acc1 + 8, v1, u1b);
            bfma8(acc0, v2, u2a); bfma8(acc0 + 8, v2, u2b);
            bfma8(acc1, v3, u3a); bfma8(acc1 + 8, v3, u3b);
        }
        for (; e < e1; ++e) {
            int cc = cols[e];
            float v = vals[e];
            short8 ua = EA8[(size_t)cc * 16 + chunk], ub = EA8[(size_t)cc * 16 + chunk + 1];
            bfma8(acc0, v, ua); bfma8(acc0 + 8, v, ub);
        }
        short8 s0, s1;
#pragma unroll
        for (int i = 0; i < 8; ++i) {
            s0[i] = (short)f2bf(acc0[i] + acc1[i]);
            s1[i] = (short)f2bf(acc0[8 + i] + acc1[8 + i]);
        }
        *(short8*)(&SS[grp * SPAD + l8 * 16]) = s0;
        *(short8*)(&SS[grp * SPAD + l8 * 16 + 8]) = s1;
        __syncthreads();
    }

    // per-col bias (+ folded rank-1 avg term)
    float bv = bias[col];
    if (c.accin >= 0) {
        const float* accin = A.ACC + c.accin * 128;
        const float* Wb = A.lrW + (size_t)c.wb * 32768 + 16384;
        float inv = 1.f / A.DEN[0];
#pragma unroll 4
        for (int k = 0; k < F; ++k) bv += (accin[k] * inv) * Wb[k * F + col];
    }

    f32x16 acc;
#pragma unroll
    for (int i = 0; i < 16; ++i) acc[i] = 0.f;
#pragma unroll
    for (int ki = 0; ki < 8; ++ki) {
        short8 b = *(const short8*)(Wp + (size_t)(((ki * 4 + w) * 64 + l) * 8));
        acc = __builtin_amdgcn_mfma_f32_32x32x16_bf16(afrag[ki], b, acc, 0, 0, 0);
    }
    if (lap) {
        const ushort* ssr = &SS[m * SPAD + kh * 8];
#pragma unroll
        for (int ki = 0; ki < 8; ++ki) {
            short8 aa = *(const short8*)(ssr + ki * 16);
            short8 b = *(const short8*)(Wp + 16384 + (size_t)(((ki * 4 + w) * 64 + l) * 8));
            acc = __builtin_amdgcn_mfma_f32_32x32x16_bf16(aa, b, acc, 0, 0, 0);
        }
    }

    float outv[16];
#pragma unroll
    for (int reg = 0; reg < 16; ++reg) {
        int r = (reg & 3) + 8 * (reg >> 2) + 4 * kh;
        size_t rg = (size_t)(rbase + r);
        float v = acc[reg] + bv;
        if (RES) v += RES[rg * F + col];
        outv[reg] = v;
        if (OUT) OUT[rg * F + col] = v;
        if (EAOUT) EAOUT[rg * F + col] = f2bf(elu_f(v));
    }
    if (c.accout >= 0) {
        float* accout = A.ACC + c.accout * 128;
        float p = 0.f;
#pragma unroll
        for (int reg = 0; reg < 16; ++reg) {
            int r = (reg & 3) + 8 * (reg >> 2) + 4 * kh;
            p += elu_f(outv[reg]) * A.mask[rbase + r];
        }
        p += __shfl_xor(p, 32, 64);
        if (l < 32) atomicAdd(accout + col, p);
    }
    if (c.epi == 1) {          // fused maxpool2
        float* EO = FB[c.eo]; ushort* EE = EB[c.ee];
        int rb2 = rbase >> 1;
#pragma unroll
        for (int q = 0; q < 4; ++q)
#pragma unroll
            for (int e2 = 0; e2 < 2; ++e2) {
                float pv = fmaxf(outv[q * 4 + e2 * 2], outv[q * 4 + e2 * 2 + 1]);
                size_t idx = (size_t)(rb2 + q * 4 + kh * 2 + e2) * F + col;
                EO[idx] = pv;
                EE[idx] = f2bf(elu_f(pv));
            }
    } else if (c.epi == 2) {   // fused repeat2 + skip add
        float* EO = FB[c.eo]; ushort* EE = EB[c.ee];
        const float* SK = FB[c.skip];
#pragma unroll
        for (int reg = 0; reg < 16; ++reg) {
            int r = (reg & 3) + 8 * (reg >> 2) + 4 * kh;
            size_t R0 = (size_t)(2 * (rbase + r)) * F + col;
            float v0 = outv[reg] + SK[R0];
            float v1 = outv[reg] + SK[R0 + F];
            EO[R0] = v0;     EO[R0 + F] = v1;
            EE[R0] = f2bf(elu_f(v0)); EE[R0 + F] = f2bf(elu_f(v1));
        }
    }
}

__global__ __launch_bounds__(256, 3)
void mega_kernel(MArgs A) {
    __shared__ ushort SS[NR * SPAD];
    __shared__ float sg_s[4], sl_s[4];
    cg::grid_group grid = cg::this_grid();
    const int t = threadIdx.x;
    const int gsz = gridDim.x;

    float* FB[7] = {A.BUF0, A.GU, A.G2, A.D8, A.D4, A.D2, A.LB};
    ushort* EBb[8] = {A.EB0, A.EG1, A.EG2, A.ED8, A.ED4, A.ED2, A.LE1, A.LE2};
    const float* BB[4] = {A.gdb, A.glb, A.gub, A.lrb};

    // ---- stage 0: setup (weight pack + rowptr + denom + ACC zero) ----
    for (int b = blockIdx.x; b < 274; b += gsz) {
        if (b < 88) {
            const float* src; int lb;
            if (b < 12)      { src = A.gdW; lb = b; }
            else if (b < 16) { src = A.glW; lb = b - 12; }
            else if (b < 28) { src = A.guW; lb = b - 16; }
            else             { src = A.lrW; lb = b - 28; }
            src += (size_t)lb * 16384;
            ushort* dst = A.P + (size_t)b * 16384;
            for (int idx = t; idx < 16384; idx += 256) {
                int k = idx >> 7, nn = idx & 127;
                int k0 = k >> 4, rk = k & 15, j = rk & 7, lh = rk >> 3;
                int n0 = nn >> 5, ll = nn & 31;
                dst[((k0 * 4 + n0) * 64 + lh * 32 + ll) * 8 + j] = f2bf(src[idx]);
            }
        } else if (b < 273) {
            int tid = (b - 88) * 256 + t;
            const int ns[5] = {2048, 4096, 8192, 16384, 16384};
            const int es[5] = {16384, 32768, 65536, 131072, 131072};
            int base = 0;
            for (int lv = 0; lv < 5; ++lv) {
                int cnt = ns[lv] + 1;
                if (tid < base + cnt) {
                    int r = tid - base;
                    const int* rows = A.rows[lv]; int e = es[lv];
                    int lo = 0, hi = e;
                    while (lo < hi) { int mid = (lo + hi) >> 1; if (rows[mid] < r) lo = mid + 1; else hi = mid; }
                    A.rp[lv][r] = lo;
                    break;
                }
                base += cnt;
            }
        } else {
            __shared__ float red[256];
            float ssum = 0.f;
            for (int i = t; i < 16384; i += 256) ssum += A.mask[i];
            red[t] = ssum; __syncthreads();
            for (int st = 128; st > 0; st >>= 1) { if (t < st) red[t] += red[t + st]; __syncthreads(); }
            if (t == 0) A.DEN[0] = red[0];
            for (int i = t; i < 1792; i += 256) A.ACC[i] = 0.f;
        }
    }
    grid.sync();

    // ---- stage 1: both conv1s ----
    for (int id = blockIdx.x * 256 + t; id < 16384 * F; id += gsz * 256) {
        int r = id >> 7, c = id & 127;
        float x0 = A.inputs[r * 3 + 0], x1 = A.inputs[r * 3 + 1], x2 = A.inputs[r * 3 + 2];
        float g = x0 * A.gW1[c] + x1 * A.gW1[F + c] + x2 * A.gW1[2 * F + c] + A.gb1[c];
        float lo = x0 * A.lW1[c] + x1 * A.lW1[F + c] + x2 * A.lW1[2 * F + c] + A.lb1[c];
        A.BUF0[id] = g;  A.EB0[id] = f2bf(elu_f(g));
        A.LB[id] = lo;   A.LE1[id] = f2bf(elu_f(lo));
    }
    grid.sync();

    // ---- 30 layer phases (global slot p<14 paired with local slot p) ----
    for (int p = 0; p < 30; ++p) {
        int ntA = (p < 14) ? GS[p].nt : 0;
        int ntB = LS[p].nt;
        for (int i = blockIdx.x; i < ntA + ntB; i += gsz) {
            if (i < ntA) run_layer_tile(A, GS[p], i, SS, FB, EBb, BB);
            else         run_layer_tile(A, LS[p], i - ntA, SS, FB, EBb, BB);
        }
        grid.sync();
    }

    // ---- final ----
    int rh = t >> 7, f = t & 127;
    for (int pr = blockIdx.x; pr < 8192; pr += gsz) {
        size_t row = (size_t)pr * 2 + rh;
        float pg = bf2f(A.EB0[row * F + f]) * A.gW2[f * 2 + 0];
        float pl = bf2f(A.LE1[row * F + f]) * A.lW2[f];
#pragma unroll
        for (int o = 32; o > 0; o >>= 1) {
            pg += __shfl_down(pg, o, 64);
            pl += __shfl_down(pl, o, 64);
        }
        int wave = t >> 6;
        if ((t & 63) == 0) { sg_s[wave] = pg; sl_s[wave] = pl; }
        __syncthreads();
        if (t < 2) {
            size_t r = (size_t)pr * 2 + t;
            float sg = sg_s[t * 2] + sg_s[t * 2 + 1] + A.gb2[0] + A.inputs[r * 3 + 0];
            float sl = sl_s[t * 2] + sl_s[t * 2 + 1] + A.lb2[0] + A.inputs[r * 3 + 0];
            float wgt = 1.f / (1.f + __expf(-sg));
            A.out[r] = sg;
            A.out[16384 + r] = sl;
            A.out[32768 + r] = wgt * sg + (1.f - wgt) * sl;
        }
        __syncthreads();
    }
}

extern "C" void kernel_launch(void* const* d_in, const int* in_sizes, int n_in,
                              void* d_out, int out_size, void* d_ws, size_t ws_size,
                              hipStream_t stream) {
    (void)in_sizes; (void)n_in; (void)out_size; (void)ws_size;
    const int N = 16384;
    const int nlev[5] = {2048, 4096, 8192, 16384, 16384};

    char* ws = (char*)d_ws;
    size_t off = 0;
    auto alloc = [&](size_t bytes) -> char* {
        char* p = ws + off;
        off = (off + bytes + 255) & ~(size_t)255;
        return p;
    };

    MArgs A;
    A.inputs = (const float*)d_in[0];
    A.mask   = (const float*)d_in[2];
    for (int i = 0; i < 5; ++i) {
        A.rows[i] = (const int*)d_in[3 + 3 * i];
        A.cols[i] = (const int*)d_in[4 + 3 * i];
        A.vals[i] = (const float*)d_in[5 + 3 * i];
    }
    A.gW1 = (const float*)d_in[18]; A.gb1 = (const float*)d_in[19];
    A.gdW = (const float*)d_in[20]; A.gdb = (const float*)d_in[21];
    A.glW = (const float*)d_in[22]; A.glb = (const float*)d_in[23];
    A.guW = (const float*)d_in[24]; A.gub = (const float*)d_in[25];
    A.gW2 = (const float*)d_in[26]; A.gb2 = (const float*)d_in[27];
    A.lW1 = (const float*)d_in[28]; A.lb1 = (const float*)d_in[29];
    A.lrW = (const float*)d_in[30]; A.lrb = (const float*)d_in[31];
    A.lW2 = (const float*)d_in[32]; A.lb2 = (const float*)d_in[33];
    A.out = (float*)d_out;

    A.BUF0 = (float*)alloc((size_t)N * F * 4);
    A.GU   = (float*)alloc((size_t)N * F * 4);
    A.G2   = (float*)alloc((size_t)N * F * 4);
    A.D8   = (float*)alloc((size_t)8192 * F * 4);
    A.D4   = (float*)alloc((size_t)4096 * F * 4);
    A.D2   = (float*)alloc((size_t)2048 * F * 4);
    A.LB   = (float*)alloc((size_t)N * F * 4);
    A.EB0  = (ushort*)alloc((size_t)N * F * 2);
    A.EG1  = (ushort*)alloc((size_t)N * F * 2);
    A.EG2  = (ushort*)alloc((size_t)N * F * 2);
    A.ED8  = (ushort*)alloc((size_t)8192 * F * 2);
    A.ED4  = (ushort*)alloc((size_t)4096 * F * 2);
    A.ED2  = (ushort*)alloc((size_t)2048 * F * 2);
    A.LE1  = (ushort*)alloc((size_t)N * F * 2);
    A.LE2  = (ushort*)alloc((size_t)N * F * 2);
    for (int i = 0; i < 5; ++i) A.rp[i] = (int*)alloc((size_t)(nlev[i] + 1) * 4);
    A.ACC = (float*)alloc(14 * 128 * 4);
    A.DEN = (float*)alloc(4);
    A.P   = (ushort*)alloc((size_t)88 * 16384 * 2);

    int nb = 0;
    hipOccupancyMaxActiveBlocksPerMultiprocessor(&nb, mega_kernel, 256, 0);
    if (nb < 1) nb = 1;
    int grid = nb * 256;
    if (grid > 768) grid = 768;

    void* params[] = { (void*)&A };
    hipLaunchCooperativeKernel((const void*)mega_kernel, dim3(grid), dim3(256),
                               params, 0, stream);
}

// Round 8
// 1060.322 us; speedup vs baseline: 1.9720x; 1.9720x over previous
//
#include <hip/hip_runtime.h>

#define F 128
#define SPAD 136      // LDS stride (ushorts) for gather S tile
#define ESPAD 132     // LDS stride (ushorts) for fused avg transform tile
#define NR 32         // rows per tile

typedef __attribute__((ext_vector_type(8))) short short8;
typedef __attribute__((ext_vector_type(16))) float f32x16;
typedef unsigned long long ull;

__device__ __forceinline__ float elu_f(float x) {
    return x > 0.f ? x : __expf(x) - 1.f;
}
__device__ __forceinline__ ushort f2bf(float x) {   // fp32 -> bf16 RNE
    unsigned u = __float_as_uint(x);
    u = (u + 0x7FFFu + ((u >> 16) & 1u)) >> 16;
    return (ushort)u;
}
__device__ __forceinline__ float bf2f(ushort u) {
    return __uint_as_float((unsigned)u << 16);
}
__device__ __forceinline__ void bfma8(float* a, float v, short8 u) {
#pragma unroll
    for (int i = 0; i < 8; ++i) a[i] += v * bf2f((ushort)u[i]);
}

// ---------------- setup: weight pack + rowptr + denom + ACC/CTR zero ----------------
struct SetupArgs {
    const float* ws0; const float* ws1; const float* ws2; const float* ws3;
    ushort* wd0; ushort* wd1; ushort* wd2; ushort* wd3;
    const int* rows0; const int* rows1; const int* rows2; const int* rows3; const int* rows4;
    int* rp0; int* rp1; int* rp2; int* rp3; int* rp4;
    const float* mask; float* den; float* acc;   // acc: 14*8*128 floats + 8 ctr ints
};

__global__ __launch_bounds__(256) void setup_kernel(SetupArgs s) {
    __shared__ ushort tile[16384];
    int b = blockIdx.x, t = threadIdx.x;
    if (b < 88) {
        const float* src; ushort* dst; int lb;
        if (b < 12)      { src = s.ws0; dst = s.wd0; lb = b; }
        else if (b < 16) { src = s.ws1; dst = s.wd1; lb = b - 12; }
        else if (b < 28) { src = s.ws2; dst = s.wd2; lb = b - 16; }
        else             { src = s.ws3; dst = s.wd3; lb = b - 28; }
        src += (size_t)lb * 16384; dst += (size_t)lb * 16384;
        for (int idx = t; idx < 16384; idx += 256) {
            int k = idx >> 7, nn = idx & 127;
            int k0 = k >> 4, rk = k & 15, j = rk & 7, lh = rk >> 3;
            int n0 = nn >> 5, ll = nn & 31;
            tile[((k0 * 4 + n0) * 64 + lh * 32 + ll) * 8 + j] = f2bf(src[idx]);
        }
        __syncthreads();
        ull* td = (ull*)dst; const ull* ts = (const ull*)tile;
        for (int i = t; i < 4096; i += 256) td[i] = ts[i];
    } else if (b < 273) {
        int tid = (b - 88) * 256 + t;
        const int ns[5] = {2048, 4096, 8192, 16384, 16384};
        const int es[5] = {16384, 32768, 65536, 131072, 131072};
        const int* rowsA[5] = {s.rows0, s.rows1, s.rows2, s.rows3, s.rows4};
        int* rpA[5] = {s.rp0, s.rp1, s.rp2, s.rp3, s.rp4};
        int base = 0;
        for (int lv = 0; lv < 5; ++lv) {
            int cnt = ns[lv] + 1;
            if (tid < base + cnt) {
                int r = tid - base;
                const int* rows = rowsA[lv]; int e = es[lv];
                int lo = 0, hi = e;
                while (lo < hi) { int mid = (lo + hi) >> 1; if (rows[mid] < r) lo = mid + 1; else hi = mid; }
                rpA[lv][r] = lo;
                return;
            }
            base += cnt;
        }
    } else {
        __shared__ float red[256];
        float ssum = 0.f;
        for (int i = t; i < 16384; i += 256) ssum += s.mask[i];
        red[t] = ssum; __syncthreads();
        for (int st = 128; st > 0; st >>= 1) { if (t < st) red[t] += red[t + st]; __syncthreads(); }
        if (t == 0) s.den[0] = red[0];
        for (int i = t; i < 14344; i += 256) s.acc[i] = 0.f;   // 14*8*128 + 8 ctr words
    }
}

// both conv1s in one pass over inputs
__global__ void conv1_dual(const float* __restrict__ in,
                           const float* __restrict__ Wg, const float* __restrict__ bg,
                           const float* __restrict__ Wl, const float* __restrict__ bl,
                           float* __restrict__ og, ushort* __restrict__ eg,
                           float* __restrict__ ol, ushort* __restrict__ el, int n) {
    int id = blockIdx.x * 256 + threadIdx.x;
    if (id >= n * F) return;
    int r = id >> 7, c = id & 127;
    float x0 = in[r * 3 + 0], x1 = in[r * 3 + 1], x2 = in[r * 3 + 2];
    float g = x0 * Wg[c] + x1 * Wg[F + c] + x2 * Wg[2 * F + c] + bg[c];
    float lo = x0 * Wl[c] + x1 * Wl[F + c] + x2 * Wl[2 * F + c] + bl[c];
    og[id] = g;  eg[id] = f2bf(elu_f(g));
    ol[id] = lo; el[id] = f2bf(elu_f(lo));
}

// ---------------- lap / up-down layer ----------------
struct LArgs {
    const ushort* EA; const float* RES; float* OUT; ushort* EAOUT;
    const int* rowptr; const int* cols; const float* vals;
    const ushort* Wp; const float* bias;
    const float* mask; float* accout;     // 8-replica base or null
    float* EO; ushort* EE; const float* SKIP;
    int epi;  // 0 none, 1 maxpool2, 2 repeat2+skip
    int fin;  // final epilogue
    const float* Finp; const ushort* FEB0;
    const float* FgW2; const float* Fgb2; const float* FlW2; const float* Flb2;
    float* Fout;
};

__device__ __forceinline__ void layer_body(const LArgs& a, int blk, ushort* SS, float* FS) {
    const int t = threadIdx.x;
    const int rbase = blk * NR;
    const int w = t >> 6, l = t & 63, m = l & 31, kh = l >> 5;
    const int col = w * 32 + m;
    const bool lap = (a.rowptr != nullptr);

    // dense-half A-fragments straight from EA global (frag-exact layout)
    short8 afrag[8];
    {
        const ushort* ear = a.EA + (size_t)(rbase + m) * F + kh * 8;
#pragma unroll
        for (int ki = 0; ki < 8; ++ki) afrag[ki] = *(const short8*)(ear + ki * 16);
    }

    if (lap) {
        const int grp = t >> 3, l8 = t & 7;
        const short8* EA8 = (const short8*)a.EA;
        const int chunk = l8 * 2;
        int row = rbase + grp;
        int e0 = a.rowptr[row], e1 = a.rowptr[row + 1];
        float acc0[16], acc1[16];
#pragma unroll
        for (int i = 0; i < 16; ++i) { acc0[i] = 0.f; acc1[i] = 0.f; }
        int e = e0;
        for (; e + 4 <= e1; e += 4) {
            int c0 = a.cols[e + 0], c1 = a.cols[e + 1], c2 = a.cols[e + 2], c3 = a.cols[e + 3];
            float v0 = a.vals[e + 0], v1 = a.vals[e + 1], v2 = a.vals[e + 2], v3 = a.vals[e + 3];
            short8 u0a = EA8[(size_t)c0 * 16 + chunk], u0b = EA8[(size_t)c0 * 16 + chunk + 1];
            short8 u1a = EA8[(size_t)c1 * 16 + chunk], u1b = EA8[(size_t)c1 * 16 + chunk + 1];
            short8 u2a = EA8[(size_t)c2 * 16 + chunk], u2b = EA8[(size_t)c2 * 16 + chunk + 1];
            short8 u3a = EA8[(size_t)c3 * 16 + chunk], u3b = EA8[(size_t)c3 * 16 + chunk + 1];
            bfma8(acc0, v0, u0a); bfma8(acc0 + 8, v0, u0b);
            bfma8(acc1, v1, u1a); bfma8(acc1 + 8, v1, u1b);
            bfma8(acc0, v2, u2a); bfma8(acc0 + 8, v2, u2b);
            bfma8(acc1, v3, u3a); bfma8(acc1 + 8, v3, u3b);
        }
        for (; e < e1; ++e) {
            int cc = a.cols[e];
            float v = a.vals[e];
            short8 ua = EA8[(size_t)cc * 16 + chunk], ub = EA8[(size_t)cc * 16 + chunk + 1];
            bfma8(acc0, v, ua); bfma8(acc0 + 8, v, ub);
        }
        short8 s0, s1;
#pragma unroll
        for (int i = 0; i < 8; ++i) {
            s0[i] = (short)f2bf(acc0[i] + acc1[i]);
            s1[i] = (short)f2bf(acc0[8 + i] + acc1[8 + i]);
        }
        *(short8*)(&SS[grp * SPAD + l8 * 16]) = s0;
        *(short8*)(&SS[grp * SPAD + l8 * 16 + 8]) = s1;
        __syncthreads();
    }

    f32x16 acc;
#pragma unroll
    for (int i = 0; i < 16; ++i) acc[i] = 0.f;
#pragma unroll
    for (int ki = 0; ki < 8; ++ki) {
        short8 b = *(const short8*)(a.Wp + (size_t)(((ki * 4 + w) * 64 + l) * 8));
        acc = __builtin_amdgcn_mfma_f32_32x32x16_bf16(afrag[ki], b, acc, 0, 0, 0);
    }
    if (lap) {
        const ushort* ssr = &SS[m * SPAD + kh * 8];
#pragma unroll
        for (int ki = 0; ki < 8; ++ki) {
            short8 aa = *(const short8*)(ssr + ki * 16);
            short8 b = *(const short8*)(a.Wp + 16384 + (size_t)(((ki * 4 + w) * 64 + l) * 8));
            acc = __builtin_amdgcn_mfma_f32_32x32x16_bf16(aa, b, acc, 0, 0, 0);
        }
    }

    const float bv = a.bias[col];
    float outv[16];
#pragma unroll
    for (int reg = 0; reg < 16; ++reg) {
        int r = (reg & 3) + 8 * (reg >> 2) + 4 * kh;
        size_t rg = (size_t)(rbase + r);
        float v = acc[reg] + bv;
        if (a.RES) v += a.RES[rg * F + col];
        outv[reg] = v;
        if (a.OUT) a.OUT[rg * F + col] = v;
        if (a.EAOUT) a.EAOUT[rg * F + col] = f2bf(elu_f(v));
    }
    if (a.accout) {
        float p = 0.f;
#pragma unroll
        for (int reg = 0; reg < 16; ++reg) {
            int r = (reg & 3) + 8 * (reg >> 2) + 4 * kh;
            p += elu_f(outv[reg]) * a.mask[rbase + r];
        }
        p += __shfl_xor(p, 32, 64);
        if (l < 32) atomicAdd(a.accout + (blk & 7) * 128 + col, p);
    }
    if (a.epi == 1) {          // fused maxpool2 (pairs lane-local)
        int rb2 = rbase >> 1;
#pragma unroll
        for (int q = 0; q < 4; ++q)
#pragma unroll
            for (int e2 = 0; e2 < 2; ++e2) {
                float pv = fmaxf(outv[q * 4 + e2 * 2], outv[q * 4 + e2 * 2 + 1]);
                size_t idx = (size_t)(rb2 + q * 4 + kh * 2 + e2) * F + col;
                a.EO[idx] = pv;
                a.EE[idx] = f2bf(elu_f(pv));
            }
    } else if (a.epi == 2) {   // fused repeat2 + skip add
#pragma unroll
        for (int reg = 0; reg < 16; ++reg) {
            int r = (reg & 3) + 8 * (reg >> 2) + 4 * kh;
            size_t R0 = (size_t)(2 * (rbase + r)) * F + col;
            float v0 = outv[reg] + a.SKIP[R0];
            float v1 = outv[reg] + a.SKIP[R0 + F];
            a.EO[R0] = v0;     a.EO[R0 + F] = v1;
            a.EE[R0] = f2bf(elu_f(v0)); a.EE[R0 + F] = f2bf(elu_f(v1));
        }
    }
    if (a.fin) {               // fused final head
        __syncthreads();
        if (t < 64) FS[t] = 0.f;
        __syncthreads();
        const float lw = a.FlW2[col];
#pragma unroll
        for (int reg = 0; reg < 16; ++reg) {
            int r = (reg & 3) + 8 * (reg >> 2) + 4 * kh;
            atomicAdd(&FS[r], elu_f(outv[reg]) * lw);
        }
        for (int idx = t; idx < 32 * 128; idx += 256) {
            int r = idx >> 7, cc = idx & 127;
            atomicAdd(&FS[32 + r], bf2f(a.FEB0[(size_t)(rbase + r) * F + cc]) * a.FgW2[2 * cc]);
        }
        __syncthreads();
        if (t < 32) {
            int rg = rbase + t;
            float base = a.Finp[rg * 3 + 0];
            float sg = FS[32 + t] + a.Fgb2[0] + base;
            float sl = FS[t] + a.Flb2[0] + base;
            float wg = 1.f / (1.f + __expf(-sg));
            a.Fout[rg] = sg;
            a.Fout[16384 + rg] = sl;
            a.Fout[32768 + rg] = wg * sg + (1.f - wg) * sl;
        }
    }
}

__global__ __launch_bounds__(256)
void dual_layer(LArgs A, LArgs B, int nA) {
    __shared__ ushort SS[NR * SPAD];
    __shared__ float FS[64];
    bool isA = (int)blockIdx.x < nA;
    const LArgs& a = isA ? A : B;
    int blk = isA ? blockIdx.x : blockIdx.x - nA;
    layer_body(a, blk, SS, FS);
}

// ---------------- fused avg block (both sub-layers, in-kernel avg barrier) ----------------
struct FArgs {
    const ushort* EA;   // LE1 in (elu of carrier)
    float* LB;          // fp32 residual carrier (in/out)
    ushort* EAOUT;      // LE1 out
    const ushort* Wp1; const ushort* Wp2;  // packed dense halves
    const float* b1; const float* b2;
    const float* Wb1; const float* Wb2;    // fp32 avg halves (128x128 row-major)
    const float* accprev;                  // slot i-1 (8 replicas, from prev dispatch)
    float* accown;                         // slot i   (8 replicas, in-kernel)
    const float* den; const float* mask;
    int* ctr;
};

__global__ __launch_bounds__(256, 2)
void fused_avg(FArgs a) {
    __shared__ ushort ES[NR * ESPAD];
    __shared__ float AP[128];
    __shared__ float BF[128];
    const int t = threadIdx.x, blk = blockIdx.x;
    const int rbase = blk * NR;
    const int w = t >> 6, l = t & 63, m = l & 31, kh = l >> 5;
    const int col = w * 32 + m;

    // prev-slot avg vector (written by previous dispatch; boundary-coherent)
    if (t < 128) {
        float s = 0.f;
#pragma unroll
        for (int r = 0; r < 8; ++r) s += a.accprev[r * 128 + t];
        AP[t] = s;
    }
    short8 af[8];
    {
        const ushort* ear = a.EA + (size_t)(rbase + m) * F + kh * 8;
#pragma unroll
        for (int ki = 0; ki < 8; ++ki) af[ki] = *(const short8*)(ear + ki * 16);
    }
    __syncthreads();
    const float inv = 1.f / a.den[0];
    if (t < 128) {
        float s = a.b1[t];
#pragma unroll 4
        for (int k = 0; k < 128; ++k) s += (AP[k] * inv) * a.Wb1[k * 128 + t];
        BF[t] = s;
    }
    __syncthreads();

    f32x16 acc;
#pragma unroll
    for (int i = 0; i < 16; ++i) acc[i] = 0.f;
#pragma unroll
    for (int ki = 0; ki < 8; ++ki) {
        short8 b = *(const short8*)(a.Wp1 + (size_t)(((ki * 4 + w) * 64 + l) * 8));
        acc = __builtin_amdgcn_mfma_f32_32x32x16_bf16(af[ki], b, acc, 0, 0, 0);
    }
    const float bv1 = BF[col];
    float outv1[16];
#pragma unroll
    for (int reg = 0; reg < 16; ++reg) outv1[reg] = acc[reg] + bv1;

    // partial masked avg of elu(out1) -> replicated ACC + release counter
    {
        float p = 0.f;
#pragma unroll
        for (int reg = 0; reg < 16; ++reg) {
            int r = (reg & 3) + 8 * (reg >> 2) + 4 * kh;
            p += elu_f(outv1[reg]) * a.mask[rbase + r];
        }
        p += __shfl_xor(p, 32, 64);
        if (l < 32) atomicAdd(a.accown + (blk & 7) * 128 + col, p);
    }
    __threadfence();
    __syncthreads();
    if (t == 0)
        __hip_atomic_fetch_add(a.ctr, 1, __ATOMIC_RELEASE, __HIP_MEMORY_SCOPE_AGENT);

    // C-layout -> A-layout transform through LDS (overlaps other blocks' work)
#pragma unroll
    for (int reg = 0; reg < 16; ++reg) {
        int r = (reg & 3) + 8 * (reg >> 2) + 4 * kh;
        ES[r * ESPAD + col] = f2bf(elu_f(outv1[reg]));
    }

    if (t == 0) {
        while (__hip_atomic_load(a.ctr, __ATOMIC_ACQUIRE, __HIP_MEMORY_SCOPE_AGENT) < 512)
            __builtin_amdgcn_s_sleep(16);
    }
    __syncthreads();

    // own-slot avg vector (coherent atomic loads)
    if (t < 128) {
        float s = 0.f;
#pragma unroll
        for (int r = 0; r < 8; ++r)
            s += __hip_atomic_load(a.accown + r * 128 + t, __ATOMIC_RELAXED,
                                   __HIP_MEMORY_SCOPE_AGENT);
        AP[t] = s;
    }
    __syncthreads();
    if (t < 128) {
        float s = a.b2[t];
#pragma unroll 4
        for (int k = 0; k < 128; ++k) s += (AP[k] * inv) * a.Wb2[k * 128 + t];
        BF[t] = s;
    }
    __syncthreads();

    f32x16 acc2;
#pragma unroll
    for (int i = 0; i < 16; ++i) acc2[i] = 0.f;
    const ushort* esr = &ES[m * ESPAD + kh * 8];
#pragma unroll
    for (int ki = 0; ki < 8; ++ki) {
        short8 aa = *(const short8*)(esr + ki * 16);
        short8 b = *(const short8*)(a.Wp2 + (size_t)(((ki * 4 + w) * 64 + l) * 8));
        acc2 = __builtin_amdgcn_mfma_f32_32x32x16_bf16(aa, b, acc2, 0, 0, 0);
    }
    const float bv2 = BF[col];
#pragma unroll
    for (int reg = 0; reg < 16; ++reg) {
        int r = (reg & 3) + 8 * (reg >> 2) + 4 * kh;
        size_t rg = (size_t)(rbase + r);
        float v = acc2[reg] + bv2 + a.LB[rg * F + col];
        a.LB[rg * F + col] = v;
        a.EAOUT[rg * F + col] = f2bf(elu_f(v));
    }
}

extern "C" void kernel_launch(void* const* d_in, const int* in_sizes, int n_in,
                              void* d_out, int out_size, void* d_ws, size_t ws_size,
                              hipStream_t stream) {
    (void)in_sizes; (void)n_in; (void)out_size; (void)ws_size;
    const float* inputs = (const float*)d_in[0];
    const float* mask1  = (const float*)d_in[2];
    const int*   lrows[5] = {(const int*)d_in[3], (const int*)d_in[6], (const int*)d_in[9],
                             (const int*)d_in[12], (const int*)d_in[15]};
    const int*   lcols[5] = {(const int*)d_in[4], (const int*)d_in[7], (const int*)d_in[10],
                             (const int*)d_in[13], (const int*)d_in[16]};
    const float* lvals[5] = {(const float*)d_in[5], (const float*)d_in[8], (const float*)d_in[11],
                             (const float*)d_in[14], (const float*)d_in[17]};
    const float* gW1 = (const float*)d_in[18];
    const float* gb1 = (const float*)d_in[19];
    const float* gdW = (const float*)d_in[20];
    const float* gdb = (const float*)d_in[21];
    const float* glW = (const float*)d_in[22];
    const float* glb = (const float*)d_in[23];
    const float* guW = (const float*)d_in[24];
    const float* gub = (const float*)d_in[25];
    const float* gW2 = (const float*)d_in[26];
    const float* gb2 = (const float*)d_in[27];
    const float* lW1 = (const float*)d_in[28];
    const float* lb1 = (const float*)d_in[29];
    const float* lrW = (const float*)d_in[30];
    const float* lrb = (const float*)d_in[31];
    const float* lW2 = (const float*)d_in[32];
    const float* lb2 = (const float*)d_in[33];
    float* out = (float*)d_out;

    const int N = 16384;
    const int nlev[5] = {2048, 4096, 8192, 16384, 16384};

    char* ws = (char*)d_ws;
    size_t off = 0;
    auto alloc = [&](size_t bytes) -> char* {
        char* p = ws + off;
        off = (off + bytes + 255) & ~(size_t)255;
        return p;
    };
    float* BUF0 = (float*)alloc((size_t)N * F * 4);
    float* GU   = (float*)alloc((size_t)N * F * 4);
    float* G2   = (float*)alloc((size_t)N * F * 4);
    float* D8   = (float*)alloc((size_t)8192 * F * 4);
    float* D4   = (float*)alloc((size_t)4096 * F * 4);
    float* D2   = (float*)alloc((size_t)2048 * F * 4);
    float* LB   = (float*)alloc((size_t)N * F * 4);
    ushort* EB0 = (ushort*)alloc((size_t)N * F * 2);
    ushort* EG1 = (ushort*)alloc((size_t)N * F * 2);
    ushort* EG2 = (ushort*)alloc((size_t)N * F * 2);
    ushort* ED8 = (ushort*)alloc((size_t)8192 * F * 2);
    ushort* ED4 = (ushort*)alloc((size_t)4096 * F * 2);
    ushort* ED2 = (ushort*)alloc((size_t)2048 * F * 2);
    ushort* LE1 = (ushort*)alloc((size_t)N * F * 2);
    ushort* LE2 = (ushort*)alloc((size_t)N * F * 2);
    int* rp[5];
    for (int i = 0; i < 5; ++i) rp[i] = (int*)alloc((size_t)(nlev[i] + 1) * 4);
    float* ACC = (float*)alloc((14 * 8 * 128 + 8) * 4);   // replicas + counters
    int* CTR = (int*)(ACC + 14 * 8 * 128);
    float* DEN = (float*)alloc(4);
    ushort* Pd = (ushort*)alloc((size_t)12 * 16384 * 2);
    ushort* Pl = (ushort*)alloc((size_t)4  * 16384 * 2);
    ushort* Pu = (ushort*)alloc((size_t)12 * 16384 * 2);
    ushort* Pr = (ushort*)alloc((size_t)60 * 16384 * 2);

    SetupArgs sa;
    sa.ws0 = gdW; sa.ws1 = glW; sa.ws2 = guW; sa.ws3 = lrW;
    sa.wd0 = Pd;  sa.wd1 = Pl;  sa.wd2 = Pu;  sa.wd3 = Pr;
    sa.rows0 = lrows[0]; sa.rows1 = lrows[1]; sa.rows2 = lrows[2];
    sa.rows3 = lrows[3]; sa.rows4 = lrows[4];
    sa.rp0 = rp[0]; sa.rp1 = rp[1]; sa.rp2 = rp[2]; sa.rp3 = rp[3]; sa.rp4 = rp[4];
    sa.mask = mask1; sa.den = DEN; sa.acc = ACC;
    setup_kernel<<<274, 256, 0, stream>>>(sa);

    conv1_dual<<<8192, 256, 0, stream>>>(inputs, gW1, gb1, lW1, lb1, BUF0, EB0, LB, LE1, N);

    const size_t WSZ = 256 * 128;   // fp32 W stride per sub-layer
    const size_t PSZ = 2 * 16384;   // packed bf16 stride per sub-layer

    auto mkL = [&](const ushort* ea, const float* res, float* o, ushort* eao,
                   int lv, const ushort* wp, const float* bias, float* accout,
                   int epi, float* eo, ushort* ee, const float* skip, int fin) {
        LArgs x;
        x.EA = ea; x.RES = res; x.OUT = o; x.EAOUT = eao;
        x.rowptr = (lv >= 0) ? rp[lv] : nullptr;
        x.cols = (lv >= 0) ? lcols[lv] : nullptr;
        x.vals = (lv >= 0) ? lvals[lv] : nullptr;
        x.Wp = wp; x.bias = bias;
        x.mask = mask1; x.accout = accout;
        x.EO = eo; x.EE = ee; x.SKIP = skip; x.epi = epi;
        x.fin = fin;
        x.Finp = inputs; x.FEB0 = EB0;
        x.FgW2 = gW2; x.Fgb2 = gb2; x.FlW2 = lW2; x.Flb2 = lb2; x.Fout = out;
        return x;
    };

    // global branch slots (pool/upadd fused), as in R6
    LArgs gs[14]; int gn[14];
    gs[0]  = mkL(EB0, 0, 0, EG1, 3, Pd + 0 * PSZ, gdb + 0,   0, 0, 0, 0, 0, 0);  gn[0]  = 16384;
    gs[1]  = mkL(EG1, BUF0, 0, 0, 3, Pd + 1 * PSZ, gdb + 128, 0, 1, D8, ED8, 0, 0); gn[1] = 16384;
    gs[2]  = mkL(ED8, 0, 0, EG1, 2, Pd + 2 * PSZ, gdb + 256, 0, 0, 0, 0, 0, 0);  gn[2]  = 8192;
    gs[3]  = mkL(EG1, D8, 0, 0, 2, Pd + 3 * PSZ, gdb + 384, 0, 1, D4, ED4, 0, 0); gn[3]  = 8192;
    gs[4]  = mkL(ED4, 0, 0, EG1, 1, Pd + 4 * PSZ, gdb + 512, 0, 0, 0, 0, 0, 0);  gn[4]  = 4096;
    gs[5]  = mkL(EG1, D4, 0, 0, 1, Pd + 5 * PSZ, gdb + 640, 0, 1, D2, ED2, 0, 0); gn[5]  = 4096;
    gs[6]  = mkL(ED2, 0, 0, EG1, 0, Pl + 0 * PSZ, glb + 0,   0, 0, 0, 0, 0, 0);  gn[6]  = 2048;
    gs[7]  = mkL(EG1, D2, 0, 0, 0, Pl + 1 * PSZ, glb + 128, 0, 2, GU, EG2, D4, 0); gn[7] = 2048;
    gs[8]  = mkL(EG2, 0, 0, EG1, 1, Pu + 0 * PSZ, gub + 0,   0, 0, 0, 0, 0, 0);  gn[8]  = 4096;
    gs[9]  = mkL(EG1, GU, 0, 0, 1, Pu + 1 * PSZ, gub + 128, 0, 2, G2, EG2, D8, 0); gn[9] = 4096;
    gs[10] = mkL(EG2, 0, 0, EG1, 2, Pu + 2 * PSZ, gub + 256, 0, 0, 0, 0, 0, 0);  gn[10] = 8192;
    gs[11] = mkL(EG1, G2, 0, 0, 2, Pu + 3 * PSZ, gub + 384, 0, 2, GU, EG2, BUF0, 0); gn[11] = 8192;
    gs[12] = mkL(EG2, 0, 0, EG1, 3, Pu + 4 * PSZ, gub + 512, 0, 0, 0, 0, 0, 0);  gn[12] = 16384;
    gs[13] = mkL(EG1, GU, 0, EB0, 3, Pu + 5 * PSZ, gub + 640, 0, 0, 0, 0, 0, 0); gn[13] = 16384;

    int gi = 0;
    auto launchLap = [&](const LArgs& loc) {
        if (gi < 14) {
            int na = gn[gi] / NR;
            dual_layer<<<na + 512, 256, 0, stream>>>(gs[gi], loc, na);
            ++gi;
        } else {
            dual_layer<<<512, 256, 0, stream>>>(loc, loc, 512);
        }
    };

    for (int i = 0; i < 15; ++i) {
        if ((i & 1) == 0) {   // lap block on L (level 4)
            LArgs s1 = mkL(LE1, 0, 0, LE2, 4, Pr + (size_t)(2 * i) * PSZ,
                           lrb + (size_t)i * 256, 0, 0, 0, 0, 0, 0);
            float* accout = (i <= 12) ? (ACC + (size_t)i * 1024) : nullptr;
            int fin = (i == 14);
            LArgs s2 = mkL(LE2, LB, fin ? nullptr : LB, fin ? nullptr : LE1, 4,
                           Pr + (size_t)(2 * i + 1) * PSZ, lrb + (size_t)i * 256 + 128,
                           accout, 0, 0, 0, 0, fin);
            launchLap(s1);
            launchLap(s2);
        } else {              // fused avg block (solo dispatch, in-kernel barrier)
            FArgs fa;
            fa.EA = LE1; fa.LB = LB; fa.EAOUT = LE1;
            fa.Wp1 = Pr + (size_t)(2 * i) * PSZ;
            fa.Wp2 = Pr + (size_t)(2 * i + 1) * PSZ;
            fa.b1 = lrb + (size_t)i * 256;
            fa.b2 = lrb + (size_t)i * 256 + 128;
            fa.Wb1 = lrW + (size_t)(2 * i) * WSZ + 16384;
            fa.Wb2 = lrW + (size_t)(2 * i + 1) * WSZ + 16384;
            fa.accprev = ACC + (size_t)(i - 1) * 1024;
            fa.accown  = ACC + (size_t)i * 1024;
            fa.den = DEN; fa.mask = mask1;
            fa.ctr = CTR + (i >> 1);
            fused_avg<<<512, 256, 0, stream>>>(fa);
        }
    }
}

// Round 9
// 684.715 us; speedup vs baseline: 3.0537x; 1.5486x over previous
//
#include <hip/hip_runtime.h>

#define F 128
#define SPAD 136      // LDS stride (ushorts) for gather S tile
#define NR 32         // rows per tile

typedef __attribute__((ext_vector_type(8))) short short8;
typedef __attribute__((ext_vector_type(16))) float f32x16;
typedef unsigned long long ull;

__device__ __forceinline__ float elu_f(float x) {
    return x > 0.f ? x : __expf(x) - 1.f;
}
__device__ __forceinline__ ushort f2bf(float x) {   // fp32 -> bf16 RNE
    unsigned u = __float_as_uint(x);
    u = (u + 0x7FFFu + ((u >> 16) & 1u)) >> 16;
    return (ushort)u;
}
__device__ __forceinline__ float bf2f(ushort u) {
    return __uint_as_float((unsigned)u << 16);
}
__device__ __forceinline__ void bfma8(float* a, float v, short8 u) {
#pragma unroll
    for (int i = 0; i < 8; ++i) a[i] += v * bf2f((ushort)u[i]);
}

// ---------------- setup: weight pack + rowptr + denom + ACC zero ----------------
struct SetupArgs {
    const float* ws0; const float* ws1; const float* ws2; const float* ws3;
    ushort* wd0; ushort* wd1; ushort* wd2; ushort* wd3;
    const int* rows0; const int* rows1; const int* rows2; const int* rows3; const int* rows4;
    int* rp0; int* rp1; int* rp2; int* rp3; int* rp4;
    const float* mask; float* den; float* acc;   // acc: 14*8*128 floats
};

__global__ __launch_bounds__(256) void setup_kernel(SetupArgs s) {
    __shared__ ushort tile[16384];
    int b = blockIdx.x, t = threadIdx.x;
    if (b < 88) {
        const float* src; ushort* dst; int lb;
        if (b < 12)      { src = s.ws0; dst = s.wd0; lb = b; }
        else if (b < 16) { src = s.ws1; dst = s.wd1; lb = b - 12; }
        else if (b < 28) { src = s.ws2; dst = s.wd2; lb = b - 16; }
        else             { src = s.ws3; dst = s.wd3; lb = b - 28; }
        src += (size_t)lb * 16384; dst += (size_t)lb * 16384;
        for (int idx = t; idx < 16384; idx += 256) {
            int k = idx >> 7, nn = idx & 127;
            int k0 = k >> 4, rk = k & 15, j = rk & 7, lh = rk >> 3;
            int n0 = nn >> 5, ll = nn & 31;
            tile[((k0 * 4 + n0) * 64 + lh * 32 + ll) * 8 + j] = f2bf(src[idx]);
        }
        __syncthreads();
        ull* td = (ull*)dst; const ull* ts = (const ull*)tile;
        for (int i = t; i < 4096; i += 256) td[i] = ts[i];
    } else if (b < 273) {
        int tid = (b - 88) * 256 + t;
        const int ns[5] = {2048, 4096, 8192, 16384, 16384};
        const int es[5] = {16384, 32768, 65536, 131072, 131072};
        const int* rowsA[5] = {s.rows0, s.rows1, s.rows2, s.rows3, s.rows4};
        int* rpA[5] = {s.rp0, s.rp1, s.rp2, s.rp3, s.rp4};
        int base = 0;
        for (int lv = 0; lv < 5; ++lv) {
            int cnt = ns[lv] + 1;
            if (tid < base + cnt) {
                int r = tid - base;
                const int* rows = rowsA[lv]; int e = es[lv];
                int lo = 0, hi = e;
                while (lo < hi) { int mid = (lo + hi) >> 1; if (rows[mid] < r) lo = mid + 1; else hi = mid; }
                rpA[lv][r] = lo;
                return;
            }
            base += cnt;
        }
    } else {
        __shared__ float red[256];
        float ssum = 0.f;
        for (int i = t; i < 16384; i += 256) ssum += s.mask[i];
        red[t] = ssum; __syncthreads();
        for (int st = 128; st > 0; st >>= 1) { if (t < st) red[t] += red[t + st]; __syncthreads(); }
        if (t == 0) s.den[0] = red[0];
        for (int i = t; i < 14336; i += 256) s.acc[i] = 0.f;
    }
}

// both conv1s in one pass over inputs
__global__ void conv1_dual(const float* __restrict__ in,
                           const float* __restrict__ Wg, const float* __restrict__ bg,
                           const float* __restrict__ Wl, const float* __restrict__ bl,
                           float* __restrict__ og, ushort* __restrict__ eg,
                           float* __restrict__ ol, ushort* __restrict__ el, int n) {
    int id = blockIdx.x * 256 + threadIdx.x;
    if (id >= n * F) return;
    int r = id >> 7, c = id & 127;
    float x0 = in[r * 3 + 0], x1 = in[r * 3 + 1], x2 = in[r * 3 + 2];
    float g = x0 * Wg[c] + x1 * Wg[F + c] + x2 * Wg[2 * F + c] + bg[c];
    float lo = x0 * Wl[c] + x1 * Wl[F + c] + x2 * Wl[2 * F + c] + bl[c];
    og[id] = g;  eg[id] = f2bf(elu_f(g));
    ol[id] = lo; el[id] = f2bf(elu_f(lo));
}

// ---------------- unified layer ----------------
// Three modes: lap (rowptr!=0, gather S-tile + 16 MFMA), avg (accin!=0, broadcast
// avg row + 16 MFMA against the same packed Wb half), plain dense (8 MFMA).
struct LArgs {
    const ushort* EA; const float* RES; float* OUT; ushort* EAOUT;
    const int* rowptr; const int* cols; const float* vals;
    const ushort* Wp; const float* bias;
    const float* accin; const float* den;    // avg mode: 8-replica ACC of prev slot
    const float* mask; float* accout;        // 8-replica out
    float* EO; ushort* EE; const float* SKIP;
    int epi;  // 0 none, 1 maxpool2, 2 repeat2+skip
    int fin;  // final-head epilogue
    const float* Finp; const ushort* FEB0;
    const float* FgW2; const float* Fgb2; const float* FlW2; const float* Flb2;
    float* Fout;
};

__device__ __forceinline__ void layer_body(const LArgs& a, int blk, ushort* SS, float* FS) {
    const int t = threadIdx.x;
    const int rbase = blk * NR;
    const int w = t >> 6, l = t & 63, m = l & 31, kh = l >> 5;
    const int col = w * 32 + m;
    const bool lap = (a.rowptr != nullptr);
    const bool avg = (a.accin != nullptr);

    // dense-half A-fragments straight from EA global (frag-exact layout)
    short8 afrag[8];
    {
        const ushort* ear = a.EA + (size_t)(rbase + m) * F + kh * 8;
#pragma unroll
        for (int ki = 0; ki < 8; ++ki) afrag[ki] = *(const short8*)(ear + ki * 16);
    }

    if (lap) {
        const int grp = t >> 3, l8 = t & 7;
        const short8* EA8 = (const short8*)a.EA;
        const int chunk = l8 * 2;
        int row = rbase + grp;
        int e0 = a.rowptr[row], e1 = a.rowptr[row + 1];
        float acc0[16], acc1[16];
#pragma unroll
        for (int i = 0; i < 16; ++i) { acc0[i] = 0.f; acc1[i] = 0.f; }
        int e = e0;
        for (; e + 4 <= e1; e += 4) {
            int c0 = a.cols[e + 0], c1 = a.cols[e + 1], c2 = a.cols[e + 2], c3 = a.cols[e + 3];
            float v0 = a.vals[e + 0], v1 = a.vals[e + 1], v2 = a.vals[e + 2], v3 = a.vals[e + 3];
            short8 u0a = EA8[(size_t)c0 * 16 + chunk], u0b = EA8[(size_t)c0 * 16 + chunk + 1];
            short8 u1a = EA8[(size_t)c1 * 16 + chunk], u1b = EA8[(size_t)c1 * 16 + chunk + 1];
            short8 u2a = EA8[(size_t)c2 * 16 + chunk], u2b = EA8[(size_t)c2 * 16 + chunk + 1];
            short8 u3a = EA8[(size_t)c3 * 16 + chunk], u3b = EA8[(size_t)c3 * 16 + chunk + 1];
            bfma8(acc0, v0, u0a); bfma8(acc0 + 8, v0, u0b);
            bfma8(acc1, v1, u1a); bfma8(acc1 + 8, v1, u1b);
            bfma8(acc0, v2, u2a); bfma8(acc0 + 8, v2, u2b);
            bfma8(acc1, v3, u3a); bfma8(acc1 + 8, v3, u3b);
        }
        for (; e < e1; ++e) {
            int cc = a.cols[e];
            float v = a.vals[e];
            short8 ua = EA8[(size_t)cc * 16 + chunk], ub = EA8[(size_t)cc * 16 + chunk + 1];
            bfma8(acc0, v, ua); bfma8(acc0 + 8, v, ub);
        }
        short8 s0, s1;
#pragma unroll
        for (int i = 0; i < 8; ++i) {
            s0[i] = (short)f2bf(acc0[i] + acc1[i]);
            s1[i] = (short)f2bf(acc0[8 + i] + acc1[8 + i]);
        }
        *(short8*)(&SS[grp * SPAD + l8 * 16]) = s0;
        *(short8*)(&SS[grp * SPAD + l8 * 16 + 8]) = s1;
        __syncthreads();
    } else if (avg) {
        // avg vector (8-replica sum / denom) as a broadcast bf16 A-row in LDS
        if (t < 128) {
            float s = 0.f;
#pragma unroll
            for (int r = 0; r < 8; ++r) s += a.accin[r * 128 + t];
            SS[t] = f2bf(s / a.den[0]);
        }
        __syncthreads();
    }

    f32x16 acc;
#pragma unroll
    for (int i = 0; i < 16; ++i) acc[i] = 0.f;
#pragma unroll
    for (int ki = 0; ki < 8; ++ki) {
        short8 b = *(const short8*)(a.Wp + (size_t)(((ki * 4 + w) * 64 + l) * 8));
        acc = __builtin_amdgcn_mfma_f32_32x32x16_bf16(afrag[ki], b, acc, 0, 0, 0);
    }
    if (lap || avg) {
        // lap: per-row S tile; avg: same broadcast row for every m
        const ushort* esr = lap ? &SS[m * SPAD + kh * 8] : &SS[kh * 8];
#pragma unroll
        for (int ki = 0; ki < 8; ++ki) {
            short8 aa = *(const short8*)(esr + ki * 16);
            short8 b = *(const short8*)(a.Wp + 16384 + (size_t)(((ki * 4 + w) * 64 + l) * 8));
            acc = __builtin_amdgcn_mfma_f32_32x32x16_bf16(aa, b, acc, 0, 0, 0);
        }
    }

    const float bv = a.bias[col];
    float outv[16];
#pragma unroll
    for (int reg = 0; reg < 16; ++reg) {
        int r = (reg & 3) + 8 * (reg >> 2) + 4 * kh;
        size_t rg = (size_t)(rbase + r);
        float v = acc[reg] + bv;
        if (a.RES) v += a.RES[rg * F + col];
        outv[reg] = v;
        if (a.OUT) a.OUT[rg * F + col] = v;
        if (a.EAOUT) a.EAOUT[rg * F + col] = f2bf(elu_f(v));
    }
    if (a.accout) {
        float p = 0.f;
#pragma unroll
        for (int reg = 0; reg < 16; ++reg) {
            int r = (reg & 3) + 8 * (reg >> 2) + 4 * kh;
            p += elu_f(outv[reg]) * a.mask[rbase + r];
        }
        p += __shfl_xor(p, 32, 64);
        if (l < 32) atomicAdd(a.accout + (blk & 7) * 128 + col, p);
    }
    if (a.epi == 1) {          // fused maxpool2 (pairs lane-local)
        int rb2 = rbase >> 1;
#pragma unroll
        for (int q = 0; q < 4; ++q)
#pragma unroll
            for (int e2 = 0; e2 < 2; ++e2) {
                float pv = fmaxf(outv[q * 4 + e2 * 2], outv[q * 4 + e2 * 2 + 1]);
                size_t idx = (size_t)(rb2 + q * 4 + kh * 2 + e2) * F + col;
                a.EO[idx] = pv;
                a.EE[idx] = f2bf(elu_f(pv));
            }
    } else if (a.epi == 2) {   // fused repeat2 + skip add
#pragma unroll
        for (int reg = 0; reg < 16; ++reg) {
            int r = (reg & 3) + 8 * (reg >> 2) + 4 * kh;
            size_t R0 = (size_t)(2 * (rbase + r)) * F + col;
            float v0 = outv[reg] + a.SKIP[R0];
            float v1 = outv[reg] + a.SKIP[R0 + F];
            a.EO[R0] = v0;     a.EO[R0 + F] = v1;
            a.EE[R0] = f2bf(elu_f(v0)); a.EE[R0 + F] = f2bf(elu_f(v1));
        }
    }
    if (a.fin) {               // fused final head
        __syncthreads();
        if (t < 64) FS[t] = 0.f;
        __syncthreads();
        const float lw = a.FlW2[col];
#pragma unroll
        for (int reg = 0; reg < 16; ++reg) {
            int r = (reg & 3) + 8 * (reg >> 2) + 4 * kh;
            atomicAdd(&FS[r], elu_f(outv[reg]) * lw);
        }
        for (int idx = t; idx < 32 * 128; idx += 256) {
            int r = idx >> 7, cc = idx & 127;
            atomicAdd(&FS[32 + r], bf2f(a.FEB0[(size_t)(rbase + r) * F + cc]) * a.FgW2[2 * cc]);
        }
        __syncthreads();
        if (t < 32) {
            int rg = rbase + t;
            float base = a.Finp[rg * 3 + 0];
            float sg = FS[32 + t] + a.Fgb2[0] + base;
            float sl = FS[t] + a.Flb2[0] + base;
            float wg = 1.f / (1.f + __expf(-sg));
            a.Fout[rg] = sg;
            a.Fout[16384 + rg] = sl;
            a.Fout[32768 + rg] = wg * sg + (1.f - wg) * sl;
        }
    }
}

__global__ __launch_bounds__(256)
void dual_layer(LArgs A, LArgs B, int nA) {
    __shared__ ushort SS[NR * SPAD];
    __shared__ float FS[64];
    bool isA = (int)blockIdx.x < nA;
    const LArgs& a = isA ? A : B;
    int blk = isA ? blockIdx.x : blockIdx.x - nA;
    layer_body(a, blk, SS, FS);
}

extern "C" void kernel_launch(void* const* d_in, const int* in_sizes, int n_in,
                              void* d_out, int out_size, void* d_ws, size_t ws_size,
                              hipStream_t stream) {
    (void)in_sizes; (void)n_in; (void)out_size; (void)ws_size;
    const float* inputs = (const float*)d_in[0];
    const float* mask1  = (const float*)d_in[2];
    const int*   lrows[5] = {(const int*)d_in[3], (const int*)d_in[6], (const int*)d_in[9],
                             (const int*)d_in[12], (const int*)d_in[15]};
    const int*   lcols[5] = {(const int*)d_in[4], (const int*)d_in[7], (const int*)d_in[10],
                             (const int*)d_in[13], (const int*)d_in[16]};
    const float* lvals[5] = {(const float*)d_in[5], (const float*)d_in[8], (const float*)d_in[11],
                             (const float*)d_in[14], (const float*)d_in[17]};
    const float* gW1 = (const float*)d_in[18];
    const float* gb1 = (const float*)d_in[19];
    const float* gdW = (const float*)d_in[20];
    const float* gdb = (const float*)d_in[21];
    const float* glW = (const float*)d_in[22];
    const float* glb = (const float*)d_in[23];
    const float* guW = (const float*)d_in[24];
    const float* gub = (const float*)d_in[25];
    const float* gW2 = (const float*)d_in[26];
    const float* gb2 = (const float*)d_in[27];
    const float* lW1 = (const float*)d_in[28];
    const float* lb1 = (const float*)d_in[29];
    const float* lrW = (const float*)d_in[30];
    const float* lrb = (const float*)d_in[31];
    const float* lW2 = (const float*)d_in[32];
    const float* lb2 = (const float*)d_in[33];
    float* out = (float*)d_out;

    const int N = 16384;
    const int nlev[5] = {2048, 4096, 8192, 16384, 16384};

    char* ws = (char*)d_ws;
    size_t off = 0;
    auto alloc = [&](size_t bytes) -> char* {
        char* p = ws + off;
        off = (off + bytes + 255) & ~(size_t)255;
        return p;
    };
    float* BUF0 = (float*)alloc((size_t)N * F * 4);
    float* GU   = (float*)alloc((size_t)N * F * 4);
    float* G2   = (float*)alloc((size_t)N * F * 4);
    float* D8   = (float*)alloc((size_t)8192 * F * 4);
    float* D4   = (float*)alloc((size_t)4096 * F * 4);
    float* D2   = (float*)alloc((size_t)2048 * F * 4);
    float* LB   = (float*)alloc((size_t)N * F * 4);
    ushort* EB0 = (ushort*)alloc((size_t)N * F * 2);
    ushort* EG1 = (ushort*)alloc((size_t)N * F * 2);
    ushort* EG2 = (ushort*)alloc((size_t)N * F * 2);
    ushort* ED8 = (ushort*)alloc((size_t)8192 * F * 2);
    ushort* ED4 = (ushort*)alloc((size_t)4096 * F * 2);
    ushort* ED2 = (ushort*)alloc((size_t)2048 * F * 2);
    ushort* LE1 = (ushort*)alloc((size_t)N * F * 2);
    ushort* LE2 = (ushort*)alloc((size_t)N * F * 2);
    int* rp[5];
    for (int i = 0; i < 5; ++i) rp[i] = (int*)alloc((size_t)(nlev[i] + 1) * 4);
    float* ACC = (float*)alloc((size_t)14 * 8 * 128 * 4);   // 8 replicas per slot
    float* DEN = (float*)alloc(4);
    ushort* Pd = (ushort*)alloc((size_t)12 * 16384 * 2);
    ushort* Pl = (ushort*)alloc((size_t)4  * 16384 * 2);
    ushort* Pu = (ushort*)alloc((size_t)12 * 16384 * 2);
    ushort* Pr = (ushort*)alloc((size_t)60 * 16384 * 2);

    SetupArgs sa;
    sa.ws0 = gdW; sa.ws1 = glW; sa.ws2 = guW; sa.ws3 = lrW;
    sa.wd0 = Pd;  sa.wd1 = Pl;  sa.wd2 = Pu;  sa.wd3 = Pr;
    sa.rows0 = lrows[0]; sa.rows1 = lrows[1]; sa.rows2 = lrows[2];
    sa.rows3 = lrows[3]; sa.rows4 = lrows[4];
    sa.rp0 = rp[0]; sa.rp1 = rp[1]; sa.rp2 = rp[2]; sa.rp3 = rp[3]; sa.rp4 = rp[4];
    sa.mask = mask1; sa.den = DEN; sa.acc = ACC;
    setup_kernel<<<274, 256, 0, stream>>>(sa);

    conv1_dual<<<8192, 256, 0, stream>>>(inputs, gW1, gb1, lW1, lb1, BUF0, EB0, LB, LE1, N);

    const size_t PSZ = 2 * 16384;   // packed bf16 stride per sub-layer (2 halves)

    auto mkL = [&](const ushort* ea, const float* res, float* o, ushort* eao,
                   int lv, const ushort* wp, const float* bias, float* accout,
                   int epi, float* eo, ushort* ee, const float* skip,
                   const float* accin, int fin) {
        LArgs x;
        x.EA = ea; x.RES = res; x.OUT = o; x.EAOUT = eao;
        x.rowptr = (lv >= 0) ? rp[lv] : nullptr;
        x.cols = (lv >= 0) ? lcols[lv] : nullptr;
        x.vals = (lv >= 0) ? lvals[lv] : nullptr;
        x.Wp = wp; x.bias = bias;
        x.accin = accin; x.den = DEN;
        x.mask = mask1; x.accout = accout;
        x.EO = eo; x.EE = ee; x.SKIP = skip; x.epi = epi;
        x.fin = fin;
        x.Finp = inputs; x.FEB0 = EB0;
        x.FgW2 = gW2; x.Fgb2 = gb2; x.FlW2 = lW2; x.Flb2 = lb2; x.Fout = out;
        return x;
    };

    // ---- global branch slots (pool/upadd fused into sub2 epilogues) ----
    LArgs gs[14]; int gn[14];
    gs[0]  = mkL(EB0, 0, 0, EG1, 3, Pd + 0 * PSZ, gdb + 0,   0, 0, 0, 0, 0, 0, 0);  gn[0]  = 16384;
    gs[1]  = mkL(EG1, BUF0, 0, 0, 3, Pd + 1 * PSZ, gdb + 128, 0, 1, D8, ED8, 0, 0, 0); gn[1] = 16384;
    gs[2]  = mkL(ED8, 0, 0, EG1, 2, Pd + 2 * PSZ, gdb + 256, 0, 0, 0, 0, 0, 0, 0);  gn[2]  = 8192;
    gs[3]  = mkL(EG1, D8, 0, 0, 2, Pd + 3 * PSZ, gdb + 384, 0, 1, D4, ED4, 0, 0, 0); gn[3]  = 8192;
    gs[4]  = mkL(ED4, 0, 0, EG1, 1, Pd + 4 * PSZ, gdb + 512, 0, 0, 0, 0, 0, 0, 0);  gn[4]  = 4096;
    gs[5]  = mkL(EG1, D4, 0, 0, 1, Pd + 5 * PSZ, gdb + 640, 0, 1, D2, ED2, 0, 0, 0); gn[5]  = 4096;
    gs[6]  = mkL(ED2, 0, 0, EG1, 0, Pl + 0 * PSZ, glb + 0,   0, 0, 0, 0, 0, 0, 0);  gn[6]  = 2048;
    gs[7]  = mkL(EG1, D2, 0, 0, 0, Pl + 1 * PSZ, glb + 128, 0, 2, GU, EG2, D4, 0, 0); gn[7] = 2048;
    gs[8]  = mkL(EG2, 0, 0, EG1, 1, Pu + 0 * PSZ, gub + 0,   0, 0, 0, 0, 0, 0, 0);  gn[8]  = 4096;
    gs[9]  = mkL(EG1, GU, 0, 0, 1, Pu + 1 * PSZ, gub + 128, 0, 2, G2, EG2, D8, 0, 0); gn[9] = 4096;
    gs[10] = mkL(EG2, 0, 0, EG1, 2, Pu + 2 * PSZ, gub + 256, 0, 0, 0, 0, 0, 0, 0);  gn[10] = 8192;
    gs[11] = mkL(EG1, G2, 0, 0, 2, Pu + 3 * PSZ, gub + 384, 0, 2, GU, EG2, BUF0, 0, 0); gn[11] = 8192;
    gs[12] = mkL(EG2, 0, 0, EG1, 3, Pu + 4 * PSZ, gub + 512, 0, 0, 0, 0, 0, 0, 0);  gn[12] = 16384;
    gs[13] = mkL(EG1, GU, 0, EB0, 3, Pu + 5 * PSZ, gub + 640, 0, 0, 0, 0, 0, 0, 0); gn[13] = 16384;

    int gi = 0;
    auto launchLap = [&](const LArgs& loc) {
        if (gi < 14) {
            int na = gn[gi] / NR;
            dual_layer<<<na + 512, 256, 0, stream>>>(gs[gi], loc, na);
            ++gi;
        } else {
            dual_layer<<<512, 256, 0, stream>>>(loc, loc, 512);
        }
    };

    for (int i = 0; i < 15; ++i) {
        const ushort* P1 = Pr + (size_t)(2 * i) * PSZ;
        const ushort* P2 = Pr + (size_t)(2 * i + 1) * PSZ;
        const float* b1 = lrb + (size_t)i * 256;
        const float* b2 = b1 + 128;
        if ((i & 1) == 0) {   // lap block on L (level 4)
            LArgs s1 = mkL(LE1, 0, 0, LE2, 4, P1, b1, 0, 0, 0, 0, 0, 0, 0);
            float* accout = (i <= 12) ? (ACC + (size_t)i * 1024) : nullptr;
            int fin = (i == 14);
            LArgs s2 = mkL(LE2, LB, fin ? nullptr : LB, fin ? nullptr : LE1, 4,
                           P2, b2, accout, 0, 0, 0, 0, 0, fin);
            launchLap(s1);
            launchLap(s2);
        } else {              // avg block: MFMA-based rank-1 fold (broadcast avg row)
            LArgs s1 = mkL(LE1, 0, 0, LE2, -1, P1, b1, ACC + (size_t)i * 1024,
                           0, 0, 0, 0, ACC + (size_t)(i - 1) * 1024, 0);
            LArgs s2 = mkL(LE2, LB, LB, LE1, -1, P2, b2, 0,
                           0, 0, 0, 0, ACC + (size_t)i * 1024, 0);
            launchLap(s1);
            launchLap(s2);
        }
    }
}